// Round 3
// baseline (145.508 us; speedup 1.0000x reference)
//
#include <hip/hip_runtime.h>
#include <math.h>

#define BB 8
#define LL 2048
#define HH 1024
#define JL 64
#define TT 1984          // LL - JL
#define NCH 31           // q2c t-chunks (1984/31 = 64)
#define TCH 64
#define PAD 68           // 68*4B = 272B row stride: 16B-aligned, rows 4 apart differ by 16 banks

// workspace layout (float offsets)
#define S_OFF   0
#define S_SZ    (BB*TT*JL)
#define QT_OFF  (S_OFF + S_SZ)
#define QT_SZ   (BB*JL)
#define M_OFF   (QT_OFF + QT_SZ)
#define M_SZ    (BB*TT)
#define BA_OFF  (M_OFF + M_SZ)
#define BA_SZ   (BB*TT)
#define QP_OFF  (BA_OFF + BA_SZ)
#define QP_SZ   (BB*NCH*HH)
#define Q2C_OFF (QP_OFF + QP_SZ)

// ---- k0: copy query to out, compute q_term[b,j] = <query[b,j,:], w_q> ----
__global__ __launch_bounds__(256) void k0(const float* __restrict__ enc,
                                          const float* __restrict__ w,
                                          float* __restrict__ out,
                                          float* __restrict__ ws) {
  int j = blockIdx.x, b = blockIdx.y, tid = threadIdx.x;
  const float* qrow = enc + ((size_t)b*LL + j)*HH;
  float4 v = *(const float4*)(qrow + tid*4);
  *(float4*)(out + ((size_t)b*JL + j)*HH + tid*4) = v;
  float4 wq = *(const float4*)(w + HH + tid*4);
  float a = v.x*wq.x + v.y*wq.y + v.z*wq.z + v.w*wq.w;
  #pragma unroll
  for (int o = 32; o > 0; o >>= 1) a += __shfl_xor(a, o);
  __shared__ float red[4];
  if ((tid & 63) == 0) red[tid >> 6] = a;
  __syncthreads();
  if (tid == 0) ws[QT_OFF + b*JL + j] = red[0]+red[1]+red[2]+red[3];
}

// ---- k1: S[b,t,j] GEMM + per-row max m[b,t] ----
// S = sum_h ctx[t,h]*(w_m[h]*q[j,h] + w_c[h]) + q_term[j]
__global__ __launch_bounds__(256) void k1(const float* __restrict__ enc,
                                          const float* __restrict__ w,
                                          float* __restrict__ ws) {
  __shared__ float ctx_s[64][PAD];   // [t_local][k]
  __shared__ float qm_t[64][PAD];    // [k][j], col XOR-swizzled
  const int b = blockIdx.y;
  const int t0 = blockIdx.x * 64;
  const int tid = threadIdx.x;
  const int tr = tid >> 4, tc = tid & 15;
  const float* ctx = enc + ((size_t)b*LL + JL)*HH;
  const float* qry = enc + (size_t)b*LL*HH;
  const float* wc = w;
  const float* wm = w + 2*HH;
  float acc[4][4] = {};
  for (int h0 = 0; h0 < HH; h0 += 64) {
    #pragma unroll
    for (int it = 0; it < 4; ++it) {
      int idx = it*256 + tid;
      int r = idx >> 4, c4 = idx & 15;
      float4 cv = *(const float4*)(ctx + (size_t)(t0 + r)*HH + h0 + c4*4);
      *(float4*)&ctx_s[r][c4*4] = cv;
      float4 q4 = *(const float4*)(qry + (size_t)r*HH + h0 + c4*4);
      float4 m4 = *(const float4*)(wm + h0 + c4*4);
      float4 w4 = *(const float4*)(wc + h0 + c4*4);
      int col = r ^ (c4*4);           // swizzle: involution per k-group
      qm_t[c4*4 + 0][col] = q4.x*m4.x + w4.x;
      qm_t[c4*4 + 1][col] = q4.y*m4.y + w4.y;
      qm_t[c4*4 + 2][col] = q4.z*m4.z + w4.z;
      qm_t[c4*4 + 3][col] = q4.w*m4.w + w4.w;
    }
    __syncthreads();
    #pragma unroll 4
    for (int k4 = 0; k4 < 16; ++k4) {
      float ar[4][4], br[4][4];
      #pragma unroll
      for (int i = 0; i < 4; ++i) {
        float4 t4 = *(const float4*)&ctx_s[tr*4+i][k4*4];
        ar[i][0]=t4.x; ar[i][1]=t4.y; ar[i][2]=t4.z; ar[i][3]=t4.w;
      }
      const int colb = 4*(tc ^ k4);
      #pragma unroll
      for (int kk = 0; kk < 4; ++kk) {
        float4 t4 = *(const float4*)&qm_t[k4*4+kk][colb];
        br[kk][0]=t4.x; br[kk][1]=t4.y; br[kk][2]=t4.z; br[kk][3]=t4.w;
      }
      #pragma unroll
      for (int kk = 0; kk < 4; ++kk)
        #pragma unroll
        for (int i = 0; i < 4; ++i)
          #pragma unroll
          for (int jj = 0; jj < 4; ++jj)
            acc[i][jj] += ar[i][kk]*br[kk][jj];
    }
    __syncthreads();
  }
  float4 qt4 = *(const float4*)(ws + QT_OFF + (size_t)b*JL + tc*4);
  float* Sp = ws + S_OFF + ((size_t)b*TT + t0)*JL;
  float* mp = ws + M_OFF + (size_t)b*TT + t0;
  #pragma unroll
  for (int i = 0; i < 4; ++i) {
    float s0 = acc[i][0] + qt4.x;
    float s1 = acc[i][1] + qt4.y;
    float s2 = acc[i][2] + qt4.z;
    float s3 = acc[i][3] + qt4.w;
    *(float4*)(Sp + (size_t)(tr*4+i)*JL + tc*4) = make_float4(s0,s1,s2,s3);
    float rm = fmaxf(fmaxf(s0,s1), fmaxf(s2,s3));
    #pragma unroll
    for (int o = 1; o < 16; o <<= 1) rm = fmaxf(rm, __shfl_xor(rm, o));
    if (tc == 0) mp[tr*4+i] = rm;
  }
}

// ---- k2: b_att[b,t] = softmax_t(m[b,t]) ----
__global__ __launch_bounds__(256) void k2(float* __restrict__ ws) {
  int b = blockIdx.x, tid = threadIdx.x;
  const float* mp = ws + M_OFF + (size_t)b*TT;
  float mloc[8];
  float bm = -1e30f;
  #pragma unroll
  for (int k = 0; k < 8; ++k) {
    int t = tid + k*256;
    mloc[k] = (t < TT) ? mp[t] : -1e30f;
    bm = fmaxf(bm, mloc[k]);
  }
  #pragma unroll
  for (int o = 32; o > 0; o >>= 1) bm = fmaxf(bm, __shfl_xor(bm, o));
  __shared__ float red[4], red2[4];
  if ((tid & 63) == 0) red[tid >> 6] = bm;
  __syncthreads();
  float M = fmaxf(fmaxf(red[0],red[1]), fmaxf(red[2],red[3]));
  float e[8]; float s = 0.f;
  #pragma unroll
  for (int k = 0; k < 8; ++k) {
    e[k] = expf(mloc[k] - M);
    if (tid + k*256 < TT) s += e[k];
  }
  #pragma unroll
  for (int o = 32; o > 0; o >>= 1) s += __shfl_xor(s, o);
  if ((tid & 63) == 0) red2[tid >> 6] = s;
  __syncthreads();
  float inv = 1.f/(red2[0]+red2[1]+red2[2]+red2[3]);
  float* ba = ws + BA_OFF + (size_t)b*TT;
  #pragma unroll
  for (int k = 0; k < 8; ++k) {
    int t = tid + k*256;
    if (t < TT) ba[t] = e[k]*inv;
  }
}

// ---- k3: partial q2c over t-chunks ----
__global__ __launch_bounds__(256) void k3(const float* __restrict__ enc,
                                          float* __restrict__ ws) {
  int ch = blockIdx.x, b = blockIdx.y, tid = threadIdx.x;
  const float* ctx = enc + ((size_t)b*LL + JL)*HH + (size_t)ch*TCH*HH;
  const float* ba = ws + BA_OFF + (size_t)b*TT + ch*TCH;
  float4 acc = make_float4(0,0,0,0);
  #pragma unroll 4
  for (int t = 0; t < TCH; ++t) {
    float a = ba[t];
    float4 v = *(const float4*)(ctx + (size_t)t*HH + tid*4);
    acc.x += a*v.x; acc.y += a*v.y; acc.z += a*v.z; acc.w += a*v.w;
  }
  *(float4*)(ws + QP_OFF + (size_t)(b*NCH + ch)*HH + tid*4) = acc;
}

// ---- k3b: reduce partials -> q2c[b,h] ----
__global__ __launch_bounds__(256) void k3b(float* __restrict__ ws) {
  int idx = blockIdx.x*256 + threadIdx.x;   // over BB*HH/4 = 2048
  int b = idx >> 8, h4 = idx & 255;
  float4 acc = make_float4(0,0,0,0);
  for (int c = 0; c < NCH; ++c) {
    float4 v = *(const float4*)(ws + QP_OFF + (size_t)(b*NCH + c)*HH + h4*4);
    acc.x += v.x; acc.y += v.y; acc.z += v.z; acc.w += v.w;
  }
  *(float4*)(ws + Q2C_OFF + (size_t)b*HH + h4*4) = acc;
}

// ---- k4: softmax_j(S) -> c2q -> G assembly (16 t-rows per block) ----
__global__ __launch_bounds__(256) void k4(const float* __restrict__ enc,
                                          const float* __restrict__ ws,
                                          float* __restrict__ out) {
  __shared__ float4 P4[16][16];
  const int b = blockIdx.y, t0 = blockIdx.x*16, tid = threadIdx.x;
  const int r = tid >> 4, sub = tid & 15;
  const float* Sp = ws + S_OFF + ((size_t)b*TT + t0)*JL;
  float4 v = *(const float4*)(Sp + (size_t)r*JL + sub*4);
  float mx = fmaxf(fmaxf(v.x,v.y), fmaxf(v.z,v.w));
  #pragma unroll
  for (int o = 1; o < 16; o <<= 1) mx = fmaxf(mx, __shfl_xor(mx, o));
  float e0 = expf(v.x-mx), e1 = expf(v.y-mx), e2 = expf(v.z-mx), e3 = expf(v.w-mx);
  float s = e0+e1+e2+e3;
  #pragma unroll
  for (int o = 1; o < 16; o <<= 1) s += __shfl_xor(s, o);
  float inv = 1.f/s;
  P4[r][sub] = make_float4(e0*inv, e1*inv, e2*inv, e3*inv);
  __syncthreads();
  const float* qry = enc + (size_t)b*LL*HH;
  const float* ctx = enc + ((size_t)b*LL + JL)*HH + (size_t)t0*HH;
  float4 acc[16];
  #pragma unroll
  for (int i = 0; i < 16; ++i) acc[i] = make_float4(0,0,0,0);
  for (int jc = 0; jc < 16; ++jc) {
    float4 q0 = *(const float4*)(qry + (size_t)(jc*4+0)*HH + tid*4);
    float4 q1 = *(const float4*)(qry + (size_t)(jc*4+1)*HH + tid*4);
    float4 q2v = *(const float4*)(qry + (size_t)(jc*4+2)*HH + tid*4);
    float4 q3 = *(const float4*)(qry + (size_t)(jc*4+3)*HH + tid*4);
    #pragma unroll
    for (int rr = 0; rr < 16; ++rr) {
      float4 p = P4[rr][jc];
      acc[rr].x += p.x*q0.x + p.y*q1.x + p.z*q2v.x + p.w*q3.x;
      acc[rr].y += p.x*q0.y + p.y*q1.y + p.z*q2v.y + p.w*q3.y;
      acc[rr].z += p.x*q0.z + p.y*q1.z + p.z*q2v.z + p.w*q3.z;
      acc[rr].w += p.x*q0.w + p.y*q1.w + p.z*q2v.w + p.w*q3.w;
    }
  }
  float4 qc = *(const float4*)(ws + Q2C_OFF + (size_t)b*HH + tid*4);
  float* G = out + (size_t)BB*JL*HH + ((size_t)b*TT + t0)*4096;
  #pragma unroll
  for (int rr = 0; rr < 16; ++rr) {
    float4 cv = *(const float4*)(ctx + (size_t)rr*HH + tid*4);
    float4 c2 = acc[rr];
    float* Gr = G + (size_t)rr*4096;
    *(float4*)(Gr + tid*4)        = cv;
    *(float4*)(Gr + 1024 + tid*4) = c2;
    *(float4*)(Gr + 2048 + tid*4) = make_float4(cv.x*c2.x, cv.y*c2.y, cv.z*c2.z, cv.w*c2.w);
    *(float4*)(Gr + 3072 + tid*4) = make_float4(cv.x*qc.x, cv.y*qc.y, cv.z*qc.z, cv.w*qc.w);
  }
}

extern "C" void kernel_launch(void* const* d_in, const int* in_sizes, int n_in,
                              void* d_out, int out_size, void* d_ws, size_t ws_size,
                              hipStream_t stream) {
  const float* enc = (const float*)d_in[0];
  const float* w   = (const float*)d_in[1];
  float* out = (float*)d_out;
  float* ws  = (float*)d_ws;
  k0<<<dim3(JL, BB), 256, 0, stream>>>(enc, w, out, ws);
  k1<<<dim3(TT/64, BB), 256, 0, stream>>>(enc, w, ws);
  k2<<<BB, 256, 0, stream>>>(ws);
  k3<<<dim3(NCH, BB), 256, 0, stream>>>(enc, ws);
  k3b<<<8, 256, 0, stream>>>(ws);
  k4<<<dim3(TT/16, BB), 256, 0, stream>>>(enc, ws, out);
}